// Round 1
// baseline (535.295 us; speedup 1.0000x reference)
//
#include <hip/hip_runtime.h>

// Problem constants: B=8, H=8, L=1024, DK=64
constexpr int SL = 1024;   // sequence length
constexpr int NBH = 64;    // B*H rows

// Workspace layout (float offsets)
constexpr int QP_OFF = 0;         // Qp [64][1024]
constexpr int KP_OFF = 65536;     // Kp [64][1024]
constexpr int Y_OFF  = 131072;    // conv outputs, 4 branches x [64][1024]
constexpr int P_OFF  = 393216;    // branch softmax outputs, 4 x [64][1024]
constexpr int QM_OFF = 655360;    // Qm [64][1024]
constexpr int KM_OFF = 720896;    // Km [64][1024]
constexpr int ST_OFF = 786432;    // BN stats [4][8][2] = 64 floats (atomic accum)
constexpr int C_OFF  = 786496;    // scalar c = dot(wbq,wbk)/8

// ---------------- K1: scalar projections Qp, Kp and scale c ----------------
__global__ __launch_bounds__(256) void k_proj(
    const float* __restrict__ Q, const float* __restrict__ K,
    const float* __restrict__ wq, const float* __restrict__ wk,
    const float* __restrict__ wbq, const float* __restrict__ wbk,
    float* __restrict__ ws)
{
    int wid  = (blockIdx.x * 256 + threadIdx.x) >> 6;  // one wave per row
    int lane = threadIdx.x & 63;
    const int nrows = 2 * NBH * SL;  // 131072
    if (wid < nrows) {
        bool isQ = wid < NBH * SL;
        int row = isQ ? wid : wid - NBH * SL;
        const float* src = isQ ? Q : K;
        const float* w   = isQ ? wq : wk;
        float v = src[row * 64 + lane] * w[lane];
        #pragma unroll
        for (int m = 32; m; m >>= 1) v += __shfl_xor(v, m);
        if (lane == 0) ws[(isQ ? QP_OFF : KP_OFF) + row] = v;
    } else if (wid == nrows) {
        float v = wbq[lane] * wbk[lane];
        #pragma unroll
        for (int m = 32; m; m >>= 1) v += __shfl_xor(v, m);
        if (lane == 0) ws[C_OFF] = v * 0.125f;  // / sqrt(64)
    }
}

// ---------------- K2: conv1d + bias, accumulate BN stats ----------------
// grid: 32 blocks = branch(4) x batch n(8). branch 0:q/F3 1:q/F9 2:k/F3 3:k/F9
__global__ __launch_bounds__(256) void k_conv(
    float* __restrict__ ws,
    const float* __restrict__ w0, const float* __restrict__ b0,
    const float* __restrict__ w1, const float* __restrict__ b1,
    const float* __restrict__ w2, const float* __restrict__ b2,
    const float* __restrict__ w3, const float* __restrict__ b3)
{
    int branch = blockIdx.x >> 3;
    int n = blockIdx.x & 7;
    const float* wp = branch == 0 ? w0 : branch == 1 ? w1 : branch == 2 ? w2 : w3;
    const float* bp = branch == 0 ? b0 : branch == 1 ? b1 : branch == 2 ? b2 : b3;
    const int F = (branch & 1) ? 9 : 3;
    const int PAD = F >> 1;
    const float* x = ws + ((branch < 2) ? QP_OFF : KP_OFF) + n * 8 * SL;

    __shared__ float xl[8][1032];   // halo of 4 each side (offset +4)
    __shared__ float wl[8 * 8 * 9];
    __shared__ float bl[8];
    __shared__ float red[512];
    int tid = threadIdx.x;
    for (int i = tid; i < 8 * 8 * F; i += 256) wl[i] = wp[i];
    if (tid < 8) bl[tid] = bp[tid];
    for (int i = tid; i < 8 * 1032; i += 256) {
        int ci = i / 1032, t = i - ci * 1032;
        int ta = t - 4;
        xl[ci][t] = (ta >= 0 && ta < SL) ? x[ci * SL + ta] : 0.f;
    }
    __syncthreads();
    int c = tid >> 5, t0 = tid & 31;
    float s1 = 0.f, s2 = 0.f;
    float* yout = ws + Y_OFF + branch * (NBH * SL) + (n * 8 + c) * SL;
    for (int i = 0; i < 32; i++) {
        int t = t0 + 32 * i;
        float acc = bl[c];
        for (int ci = 0; ci < 8; ci++) {
            const float* xr = &xl[ci][t + 4 - PAD];
            const float* wr = &wl[(c * 8 + ci) * F];
            for (int f = 0; f < F; f++) acc += wr[f] * xr[f];
        }
        yout[t] = acc;
        s1 += acc; s2 += acc * acc;
    }
    red[tid] = s1; red[256 + tid] = s2;
    __syncthreads();
    if (tid < 8) {  // threads [tid*32, tid*32+32) all have channel == tid
        float S1 = 0.f, S2 = 0.f;
        for (int j = 0; j < 32; j++) { S1 += red[tid * 32 + j]; S2 += red[256 + tid * 32 + j]; }
        atomicAdd(&ws[ST_OFF + (branch * 8 + tid) * 2],     S1);
        atomicAdd(&ws[ST_OFF + (branch * 8 + tid) * 2 + 1], S2);
    }
}

// ---------------- K3: BN(train) + softmax over L, per row ----------------
// grid: 256 blocks = branch(4) x n(8) x c(8); 256 threads, 4 elems each (float4)
__global__ __launch_bounds__(256) void k_bnsm(
    float* __restrict__ ws,
    const float* __restrict__ g0, const float* __restrict__ be0,
    const float* __restrict__ g1, const float* __restrict__ be1,
    const float* __restrict__ g2, const float* __restrict__ be2,
    const float* __restrict__ g3, const float* __restrict__ be3)
{
    int row = blockIdx.x;
    int branch = row >> 6, n = (row >> 3) & 7, c = row & 7;
    const float* gp = branch == 0 ? g0 : branch == 1 ? g1 : branch == 2 ? g2 : g3;
    const float* bp = branch == 0 ? be0 : branch == 1 ? be1 : branch == 2 ? be2 : be3;
    float s1 = ws[ST_OFF + (branch * 8 + c) * 2];
    float s2 = ws[ST_OFF + (branch * 8 + c) * 2 + 1];
    float mu  = s1 * (1.f / 8192.f);
    float var = s2 * (1.f / 8192.f) - mu * mu;   // biased var over (B, L)
    float sc = gp[c] * rsqrtf(var + 1e-5f);
    float sh = bp[c] - mu * sc;
    const float* y = ws + Y_OFF + branch * (NBH * SL) + (n * 8 + c) * SL;
    float* p       = ws + P_OFF + branch * (NBH * SL) + (n * 8 + c) * SL;
    int tid = threadIdx.x;
    float4 yv = ((const float4*)y)[tid];
    float z0 = yv.x * sc + sh, z1 = yv.y * sc + sh, z2 = yv.z * sc + sh, z3 = yv.w * sc + sh;
    float mx = fmaxf(fmaxf(z0, z1), fmaxf(z2, z3));
    __shared__ float r1[4], r2[4];
    #pragma unroll
    for (int m = 32; m; m >>= 1) mx = fmaxf(mx, __shfl_xor(mx, m));
    if ((tid & 63) == 0) r1[tid >> 6] = mx;
    __syncthreads();
    mx = fmaxf(fmaxf(r1[0], r1[1]), fmaxf(r1[2], r1[3]));
    float e0 = __expf(z0 - mx), e1 = __expf(z1 - mx), e2 = __expf(z2 - mx), e3 = __expf(z3 - mx);
    float s = e0 + e1 + e2 + e3;
    #pragma unroll
    for (int m = 32; m; m >>= 1) s += __shfl_xor(s, m);
    if ((tid & 63) == 0) r2[tid >> 6] = s;
    __syncthreads();
    s = r2[0] + r2[1] + r2[2] + r2[3];
    float r = 1.f / s;
    ((float4*)p)[tid] = make_float4(e0 * r, e1 * r, e2 * r, e3 * r);
}

// ---------------- K4: faithful concat+reshape max scramble ----------------
// Qm[i,j,k] = max_m br[(2i+(j>=4))%8][2(j&3)+(k>=512)][(2k)&1023 + m]
__global__ __launch_bounds__(256) void k_mix(float* __restrict__ ws)
{
    int idx = blockIdx.x * 256 + threadIdx.x;  // 131072 total
    int which = idx >> 16;                     // 0 = Q, 1 = K
    int r = idx & 65535;
    int i = r >> 13, j = (r >> 10) & 7, k = r & 1023;
    int n  = 2 * i + (j >= 4 ? 1 : 0);
    int br = which * 2 + (n >= 8 ? 1 : 0);
    int row = n & 7;
    int jp  = 2 * (j & 3) + (k >= 512 ? 1 : 0);
    int k2  = (2 * k) & 1023;
    const float* src = ws + P_OFF + br * (NBH * SL) + (row * 8 + jp) * SL;
    float v = fmaxf(src[k2], src[k2 + 1]);
    ws[(which ? KM_OFF : QM_OFF) + r] = v;
}

// ---------------- K5: fused attn softmax (rank-1 logits) + write attn + PV ----
// grid: 1024 blocks = bh(64) x q-tile(16 of 64 rows). 256 threads.
__global__ __launch_bounds__(256) void k_attn(
    const float* __restrict__ V, float* __restrict__ out, const float* __restrict__ ws)
{
    int bh = blockIdx.x >> 4;
    int qt = blockIdx.x & 15;
    int tid = threadIdx.x;
    __shared__ float kml[1024];
    __shared__ float aq[64], mq[64], rq[64];
    __shared__ float el[64 * 129];   // e tile [64 q][128 k], stride 129 (conflict-free)
    __shared__ float vl[128 * 64];   // V chunk
    __shared__ float red[256];
    __shared__ float rmx[4], rmn[4];

    const float* km = ws + KM_OFF + bh * SL;
    const float* qm = ws + QM_OFF + bh * SL + qt * 64;
    float c = ws[C_OFF];

    // load Km; block max/min (for exact max-subtraction: logits monotone in Km)
    float lmax = -1e30f, lmin = 1e30f;
    #pragma unroll
    for (int i = 0; i < 4; i++) {
        float v = km[tid + 256 * i];
        kml[tid + 256 * i] = v;
        lmax = fmaxf(lmax, v); lmin = fminf(lmin, v);
    }
    #pragma unroll
    for (int m = 32; m; m >>= 1) {
        lmax = fmaxf(lmax, __shfl_xor(lmax, m));
        lmin = fminf(lmin, __shfl_xor(lmin, m));
    }
    if ((tid & 63) == 0) { rmx[tid >> 6] = lmax; rmn[tid >> 6] = lmin; }
    __syncthreads();
    float kmax = fmaxf(fmaxf(rmx[0], rmx[1]), fmaxf(rmx[2], rmx[3]));
    float kmin = fminf(fminf(rmn[0], rmn[1]), fminf(rmn[2], rmn[3]));
    if (tid < 64) {
        float a = c * qm[tid];
        aq[tid] = a;
        mq[tid] = (a > 0.f) ? a * kmax : a * kmin;
    }
    __syncthreads();
    // denominators: 4 threads per q row, 256 k each
    {
        int q = tid >> 2, g = tid & 3;
        float a = aq[q], m = mq[q];
        float s = 0.f;
        const float* kp = kml + g * 256;
        for (int k = 0; k < 256; k++) s += __expf(a * kp[k] - m);
        red[tid] = s;
        __syncthreads();
        if (tid < 64) {
            float d = red[tid * 4] + red[tid * 4 + 1] + red[tid * 4 + 2] + red[tid * 4 + 3];
            rq[tid] = 1.f / d;
        }
        __syncthreads();
    }

    float acc[4][4] = {};
    int qg4 = (tid >> 4) * 4;      // this thread's 4 q rows
    int dg4 = (tid & 15) * 4;      // this thread's 4 d cols
    int q2 = tid >> 7, kk0 = tid & 127;   // e-compute mapping (coalesced attn writes)
    float* attn_out = out + 4194304 + (bh * SL + qt * 64) * SL;
    const float* vsrc = V + bh * (SL * 64);

    for (int kc = 0; kc < 8; kc++) {
        // stage V chunk (float4, coalesced)
        const float4* vs4 = (const float4*)(vsrc + kc * 128 * 64);
        float4* vld = (float4*)vl;
        #pragma unroll
        for (int i = 0; i < 8; i++) vld[tid + 256 * i] = vs4[tid + 256 * i];
        // compute e = attn values; write global (coalesced) + LDS
        for (int qp = 0; qp < 32; qp++) {
            int q = qp * 2 + q2;
            float e = __expf(aq[q] * kml[kc * 128 + kk0] - mq[q]) * rq[q];
            el[q * 129 + kk0] = e;
            attn_out[q * SL + kc * 128 + kk0] = e;
        }
        __syncthreads();
        // PV accumulate: 4q x 4d per thread
        for (int kk = 0; kk < 128; kk++) {
            float4 v4 = *(const float4*)&vl[kk * 64 + dg4];
            float e0 = el[(qg4    ) * 129 + kk];
            float e1 = el[(qg4 + 1) * 129 + kk];
            float e2 = el[(qg4 + 2) * 129 + kk];
            float e3 = el[(qg4 + 3) * 129 + kk];
            acc[0][0] += e0 * v4.x; acc[0][1] += e0 * v4.y; acc[0][2] += e0 * v4.z; acc[0][3] += e0 * v4.w;
            acc[1][0] += e1 * v4.x; acc[1][1] += e1 * v4.y; acc[1][2] += e1 * v4.z; acc[1][3] += e1 * v4.w;
            acc[2][0] += e2 * v4.x; acc[2][1] += e2 * v4.y; acc[2][2] += e2 * v4.z; acc[2][3] += e2 * v4.w;
            acc[3][0] += e3 * v4.x; acc[3][1] += e3 * v4.y; acc[3][2] += e3 * v4.z; acc[3][3] += e3 * v4.w;
        }
        __syncthreads();
    }
    // write context [64 q][64 d] tile
    float* ctx = out + (bh * SL + qt * 64) * 64;
    #pragma unroll
    for (int qi = 0; qi < 4; qi++) {
        float4 vv = make_float4(acc[qi][0], acc[qi][1], acc[qi][2], acc[qi][3]);
        *(float4*)&ctx[(qg4 + qi) * 64 + dg4] = vv;
    }
}

extern "C" void kernel_launch(void* const* d_in, const int* in_sizes, int n_in,
                              void* d_out, int out_size, void* d_ws, size_t ws_size,
                              hipStream_t stream)
{
    const float* Q      = (const float*)d_in[0];
    const float* K      = (const float*)d_in[1];
    const float* V      = (const float*)d_in[2];
    // d_in[3] = attn_mask (unused by reference)
    const float* wq     = (const float*)d_in[4];
    const float* wk     = (const float*)d_in[5];
    const float* wbq    = (const float*)d_in[6];
    const float* wbk    = (const float*)d_in[7];
    const float* cq3_w  = (const float*)d_in[8];
    const float* cq3_b  = (const float*)d_in[9];
    const float* cq9_w  = (const float*)d_in[10];
    const float* cq9_b  = (const float*)d_in[11];
    const float* ck3_w  = (const float*)d_in[12];
    const float* ck3_b  = (const float*)d_in[13];
    const float* ck9_w  = (const float*)d_in[14];
    const float* ck9_b  = (const float*)d_in[15];
    const float* bnq3_g = (const float*)d_in[16];
    const float* bnq3_b = (const float*)d_in[17];
    const float* bnq9_g = (const float*)d_in[18];
    const float* bnq9_b = (const float*)d_in[19];
    const float* bnk3_g = (const float*)d_in[20];
    const float* bnk3_b = (const float*)d_in[21];
    const float* bnk9_g = (const float*)d_in[22];
    const float* bnk9_b = (const float*)d_in[23];
    float* out = (float*)d_out;
    float* ws  = (float*)d_ws;

    // zero BN-stat accumulators (ws is re-poisoned before every launch)
    hipMemsetAsync(ws + ST_OFF, 0, 64 * sizeof(float), stream);

    k_proj<<<32769, 256, 0, stream>>>(Q, K, wq, wk, wbq, wbk, ws);
    k_conv<<<32, 256, 0, stream>>>(ws, cq3_w, cq3_b, cq9_w, cq9_b,
                                   ck3_w, ck3_b, ck9_w, ck9_b);
    k_bnsm<<<256, 256, 0, stream>>>(ws, bnq3_g, bnq3_b, bnq9_g, bnq9_b,
                                    bnk3_g, bnk3_b, bnk9_g, bnk9_b);
    k_mix<<<512, 256, 0, stream>>>(ws);
    k_attn<<<1024, 256, 0, stream>>>(V, out, ws);
}

// Round 2
// 426.387 us; speedup vs baseline: 1.2554x; 1.2554x over previous
//
#include <hip/hip_runtime.h>

// Problem constants: B=8, H=8, L=1024, DK=64
constexpr int SL = 1024;   // sequence length
constexpr int NBH = 64;    // B*H rows

// Workspace layout (float offsets)
constexpr int QP_OFF = 0;         // Qp [64][1024]
constexpr int KP_OFF = 65536;     // Kp [64][1024]
constexpr int Y_OFF  = 131072;    // conv outputs, 4 branches x [64][1024]
constexpr int P_OFF  = 393216;    // branch softmax outputs, 4 x [64][1024]
constexpr int QM_OFF = 655360;    // Qm [64][1024]
constexpr int KM_OFF = 720896;    // Km [64][1024]
constexpr int ST_OFF = 786432;    // BN stats [4][8][2] = 64 floats (atomic accum)
constexpr int C_OFF  = 786496;    // scalar c = dot(wbq,wbk)/8
constexpr int VT_OFF = 786560;    // V packed bf16 B-fragments: 4.19M ushort = 8.4 MB

typedef __attribute__((ext_vector_type(8))) short short8;
typedef __attribute__((ext_vector_type(4))) float f32x4;

__device__ inline unsigned short f2bf(float x) {
    unsigned int u = __float_as_uint(x);
    unsigned int r = (u + 0x7fff + ((u >> 16) & 1)) >> 16;  // RNE
    return (unsigned short)r;
}

// ---------------- K1: scalar projections Qp, Kp and scale c ----------------
__global__ __launch_bounds__(256) void k_proj(
    const float* __restrict__ Q, const float* __restrict__ K,
    const float* __restrict__ wq, const float* __restrict__ wk,
    const float* __restrict__ wbq, const float* __restrict__ wbk,
    float* __restrict__ ws)
{
    int wid  = (blockIdx.x * 256 + threadIdx.x) >> 6;  // one wave per row
    int lane = threadIdx.x & 63;
    const int nrows = 2 * NBH * SL;  // 131072
    if (wid < nrows) {
        bool isQ = wid < NBH * SL;
        int row = isQ ? wid : wid - NBH * SL;
        const float* src = isQ ? Q : K;
        const float* w   = isQ ? wq : wk;
        float v = src[row * 64 + lane] * w[lane];
        #pragma unroll
        for (int m = 32; m; m >>= 1) v += __shfl_xor(v, m);
        if (lane == 0) ws[(isQ ? QP_OFF : KP_OFF) + row] = v;
    } else if (wid == nrows) {
        float v = wbq[lane] * wbk[lane];
        #pragma unroll
        for (int m = 32; m; m >>= 1) v += __shfl_xor(v, m);
        if (lane == 0) ws[C_OFF] = v * 0.125f;  // / sqrt(64)
    }
}

// ---------------- K2: conv1d + bias, accumulate BN stats ----------------
// grid: 256 blocks = branch(4) x batch n(8) x seg(8). Each: 8 ch x 128 pos.
__global__ __launch_bounds__(256) void k_conv(
    float* __restrict__ ws,
    const float* __restrict__ w0, const float* __restrict__ b0,
    const float* __restrict__ w1, const float* __restrict__ b1,
    const float* __restrict__ w2, const float* __restrict__ b2,
    const float* __restrict__ w3, const float* __restrict__ b3)
{
    int branch = blockIdx.x >> 6;
    int n = (blockIdx.x >> 3) & 7;
    int seg = blockIdx.x & 7;
    int t0 = seg * 128;
    const float* wp = branch == 0 ? w0 : branch == 1 ? w1 : branch == 2 ? w2 : w3;
    const float* bp = branch == 0 ? b0 : branch == 1 ? b1 : branch == 2 ? b2 : b3;
    const int F = (branch & 1) ? 9 : 3;
    const int PAD = F >> 1;
    const float* x = ws + ((branch < 2) ? QP_OFF : KP_OFF) + n * 8 * SL;

    __shared__ float xl[8][136];    // 128 + halo 4 each side (offset +4)
    __shared__ float wl[8 * 8 * 9];
    __shared__ float bl[8];
    int tid = threadIdx.x;
    for (int i = tid; i < 8 * 8 * F; i += 256) wl[i] = wp[i];
    if (tid < 8) bl[tid] = bp[tid];
    for (int i = tid; i < 8 * 136; i += 256) {
        int ci = i >> 7;            // i / 136 approximated... must be exact:
        ci = i / 136; int tt = i - ci * 136;
        int ta = t0 + tt - 4;
        xl[ci][tt] = (ta >= 0 && ta < SL) ? x[ci * SL + ta] : 0.f;
    }
    __syncthreads();
    int c = tid >> 5, u = tid & 31;
    float s1 = 0.f, s2 = 0.f;
    float* yout = ws + Y_OFF + branch * (NBH * SL) + (n * 8 + c) * SL + t0;
    float res[4];
    #pragma unroll
    for (int q = 0; q < 4; q++) {
        int tl = u * 4 + q;
        float acc = bl[c];
        for (int ci = 0; ci < 8; ci++) {
            const float* xr = &xl[ci][tl + 4 - PAD];
            const float* wr = &wl[(c * 8 + ci) * F];
            for (int f = 0; f < F; f++) acc += wr[f] * xr[f];
        }
        res[q] = acc;
        s1 += acc; s2 += acc * acc;
    }
    *(float4*)&yout[u * 4] = make_float4(res[0], res[1], res[2], res[3]);
    #pragma unroll
    for (int m = 16; m; m >>= 1) {
        s1 += __shfl_xor(s1, m);
        s2 += __shfl_xor(s2, m);
    }
    if (u == 0) {
        atomicAdd(&ws[ST_OFF + (branch * 8 + c) * 2],     s1);
        atomicAdd(&ws[ST_OFF + (branch * 8 + c) * 2 + 1], s2);
    }
}

// ---------------- K3: BN(train) + softmax over L, per row ----------------
__global__ __launch_bounds__(256) void k_bnsm(
    float* __restrict__ ws,
    const float* __restrict__ g0, const float* __restrict__ be0,
    const float* __restrict__ g1, const float* __restrict__ be1,
    const float* __restrict__ g2, const float* __restrict__ be2,
    const float* __restrict__ g3, const float* __restrict__ be3)
{
    int row = blockIdx.x;
    int branch = row >> 6, n = (row >> 3) & 7, c = row & 7;
    const float* gp = branch == 0 ? g0 : branch == 1 ? g1 : branch == 2 ? g2 : g3;
    const float* bp = branch == 0 ? be0 : branch == 1 ? be1 : branch == 2 ? be2 : be3;
    float s1 = ws[ST_OFF + (branch * 8 + c) * 2];
    float s2 = ws[ST_OFF + (branch * 8 + c) * 2 + 1];
    float mu  = s1 * (1.f / 8192.f);
    float var = s2 * (1.f / 8192.f) - mu * mu;   // biased var over (B, L)
    float sc = gp[c] * rsqrtf(var + 1e-5f);
    float sh = bp[c] - mu * sc;
    const float* y = ws + Y_OFF + branch * (NBH * SL) + (n * 8 + c) * SL;
    float* p       = ws + P_OFF + branch * (NBH * SL) + (n * 8 + c) * SL;
    int tid = threadIdx.x;
    float4 yv = ((const float4*)y)[tid];
    float z0 = yv.x * sc + sh, z1 = yv.y * sc + sh, z2 = yv.z * sc + sh, z3 = yv.w * sc + sh;
    float mx = fmaxf(fmaxf(z0, z1), fmaxf(z2, z3));
    __shared__ float r1[4], r2[4];
    #pragma unroll
    for (int m = 32; m; m >>= 1) mx = fmaxf(mx, __shfl_xor(mx, m));
    if ((tid & 63) == 0) r1[tid >> 6] = mx;
    __syncthreads();
    mx = fmaxf(fmaxf(r1[0], r1[1]), fmaxf(r1[2], r1[3]));
    float e0 = __expf(z0 - mx), e1 = __expf(z1 - mx), e2 = __expf(z2 - mx), e3 = __expf(z3 - mx);
    float s = e0 + e1 + e2 + e3;
    #pragma unroll
    for (int m = 32; m; m >>= 1) s += __shfl_xor(s, m);
    if ((tid & 63) == 0) r2[tid >> 6] = s;
    __syncthreads();
    s = r2[0] + r2[1] + r2[2] + r2[3];
    float r = 1.f / s;
    ((float4*)p)[tid] = make_float4(e0 * r, e1 * r, e2 * r, e3 * r);
}

// ---------------- K4: faithful concat+reshape max scramble ----------------
__global__ __launch_bounds__(256) void k_mix(float* __restrict__ ws)
{
    int idx = blockIdx.x * 256 + threadIdx.x;  // 131072 total
    int which = idx >> 16;                     // 0 = Q, 1 = K
    int r = idx & 65535;
    int i = r >> 13, j = (r >> 10) & 7, k = r & 1023;
    int n  = 2 * i + (j >= 4 ? 1 : 0);
    int br = which * 2 + (n >= 8 ? 1 : 0);
    int row = n & 7;
    int jp  = 2 * (j & 3) + (k >= 512 ? 1 : 0);
    int k2  = (2 * k) & 1023;
    const float* src = ws + P_OFF + br * (NBH * SL) + (row * 8 + jp) * SL;
    float v = fmaxf(src[k2], src[k2 + 1]);
    ws[(which ? KM_OFF : QM_OFF) + r] = v;
}

// ---------------- K4b: pack V into bf16 B-fragment order ----------------
// Layout: [bh][chunk4][dsub4][kstep8][lane64][j8]
// element = V[bh][k = chunk*256 + kstep*32 + (lane>>4)*8 + j][d = dsub*16 + (lane&15)]
__global__ __launch_bounds__(256) void k_vpack(const float* __restrict__ V, float* __restrict__ ws)
{
    int t = blockIdx.x * 256 + threadIdx.x;    // 524288 total
    int lane = t & 63;
    int s    = (t >> 6) & 7;
    int dsub = (t >> 9) & 3;
    int chunk= (t >> 11) & 3;
    int bh   = t >> 13;
    const float* vb = V + bh * (SL * 64);
    int k0 = chunk * 256 + s * 32 + (lane >> 4) * 8;
    int d  = dsub * 16 + (lane & 15);
    unsigned short o[8];
    #pragma unroll
    for (int j = 0; j < 8; j++) o[j] = f2bf(vb[(k0 + j) * 64 + d]);
    unsigned short* vt = (unsigned short*)(ws + VT_OFF);
    *(short8*)(vt + (size_t)t * 8) = *(short8*)o;
}

// ---------------- K5: fused rank-1 attn softmax + attn write + MFMA PV ----
// grid: 1024 blocks = bh(64) x q-tile(16 of 64 rows). 256 threads = 4 waves.
// Wave w owns q-subtile [qt*64 + w*16, +16).
__global__ __launch_bounds__(256) void k_attn(
    float* __restrict__ out, const float* __restrict__ ws)
{
    int bh = blockIdx.x >> 4;
    int qt = blockIdx.x & 15;
    int tid = threadIdx.x;
    __shared__ float kml[1024];
    __shared__ float aq[64], mq[64], rq[64];
    __shared__ unsigned short bpk[4 * 8 * 64 * 8];   // 32 KB B-fragment chunk
    __shared__ float red[256];
    __shared__ float rmx[4], rmn[4];

    const float* km = ws + KM_OFF + bh * SL;
    const float* qm = ws + QM_OFF + bh * SL + qt * 64;
    float c = ws[C_OFF];

    // load Km; block max/min (logits monotone in Km -> exact max subtraction)
    float lmax = -1e30f, lmin = 1e30f;
    #pragma unroll
    for (int i = 0; i < 4; i++) {
        float v = km[tid + 256 * i];
        kml[tid + 256 * i] = v;
        lmax = fmaxf(lmax, v); lmin = fminf(lmin, v);
    }
    #pragma unroll
    for (int m = 32; m; m >>= 1) {
        lmax = fmaxf(lmax, __shfl_xor(lmax, m));
        lmin = fminf(lmin, __shfl_xor(lmin, m));
    }
    if ((tid & 63) == 0) { rmx[tid >> 6] = lmax; rmn[tid >> 6] = lmin; }
    __syncthreads();
    float kmax = fmaxf(fmaxf(rmx[0], rmx[1]), fmaxf(rmx[2], rmx[3]));
    float kmin = fminf(fminf(rmn[0], rmn[1]), fminf(rmn[2], rmn[3]));
    if (tid < 64) {
        float a = c * qm[tid];
        aq[tid] = a;
        mq[tid] = (a > 0.f) ? a * kmax : a * kmin;
    }
    __syncthreads();
    // denominators: 4 threads per q row, 256 k each
    {
        int q = tid >> 2, g = tid & 3;
        float a = aq[q], m = mq[q];
        float s = 0.f;
        const float* kp = kml + g * 256;
        for (int k = 0; k < 256; k++) s += __expf(a * kp[k] - m);
        red[tid] = s;
        __syncthreads();
        if (tid < 64) {
            float d = red[tid * 4] + red[tid * 4 + 1] + red[tid * 4 + 2] + red[tid * 4 + 3];
            rq[tid] = 1.f / d;
        }
        __syncthreads();
    }

    int w = tid >> 6, lane = tid & 63;
    int m16 = lane & 15, kg = lane >> 4;
    int qloc = w * 16 + m16;                      // this lane's q row (A-frag m)
    float a = aq[qloc], mm = mq[qloc], rr = rq[qloc];
    float* attn_row = out + 4194304 + ((size_t)(bh * SL + qt * 64 + qloc)) * SL;
    const uint4* vt4 = (const uint4*)((const unsigned short*)(ws + VT_OFF) + (size_t)bh * 4 * 16384);

    f32x4 acc0 = {0,0,0,0}, acc1 = {0,0,0,0}, acc2 = {0,0,0,0}, acc3 = {0,0,0,0};

    for (int ch = 0; ch < 4; ch++) {
        // stage 32 KB of packed V-fragments (linear, conflict-free)
        const uint4* src = vt4 + ch * 2048;
        uint4* dst = (uint4*)bpk;
        #pragma unroll
        for (int i = 0; i < 8; i++) dst[tid + 256 * i] = src[tid + 256 * i];
        __syncthreads();

        #pragma unroll
        for (int s = 0; s < 8; s++) {
            int k0 = ch * 256 + s * 32 + kg * 8;
            const float* kp = kml + k0;
            float e[8];
            #pragma unroll
            for (int j = 0; j < 8; j++) e[j] = __expf(a * kp[j] - mm) * rr;
            // write attn (fp32, exact): 2x float4, 16B/lane
            *(float4*)(attn_row + k0)     = make_float4(e[0], e[1], e[2], e[3]);
            *(float4*)(attn_row + k0 + 4) = make_float4(e[4], e[5], e[6], e[7]);
            // A fragment in bf16 (lane computes exactly its own fragment)
            unsigned short af[8];
            #pragma unroll
            for (int j = 0; j < 8; j++) af[j] = f2bf(e[j]);
            short8 av = *(short8*)af;
            const short8* bbase = (const short8*)bpk + s * 64 + lane;
            short8 b0 = bbase[0 * 512];
            short8 b1 = bbase[1 * 512];
            short8 b2 = bbase[2 * 512];
            short8 b3 = bbase[3 * 512];
            acc0 = __builtin_amdgcn_mfma_f32_16x16x32_bf16(av, b0, acc0, 0, 0, 0);
            acc1 = __builtin_amdgcn_mfma_f32_16x16x32_bf16(av, b1, acc1, 0, 0, 0);
            acc2 = __builtin_amdgcn_mfma_f32_16x16x32_bf16(av, b2, acc2, 0, 0, 0);
            acc3 = __builtin_amdgcn_mfma_f32_16x16x32_bf16(av, b3, acc3, 0, 0, 0);
        }
        __syncthreads();
    }
    // epilogue: C layout col=lane&15 (d), row=(lane>>4)*4+reg (q)
    float* ctx = out + ((size_t)(bh * SL + qt * 64 + w * 16)) * 64;
    #pragma unroll
    for (int reg = 0; reg < 4; reg++) {
        int row = kg * 4 + reg;
        float* cp = ctx + row * 64 + m16;
        cp[0]  = acc0[reg];
        cp[16] = acc1[reg];
        cp[32] = acc2[reg];
        cp[48] = acc3[reg];
    }
}

extern "C" void kernel_launch(void* const* d_in, const int* in_sizes, int n_in,
                              void* d_out, int out_size, void* d_ws, size_t ws_size,
                              hipStream_t stream)
{
    const float* Q      = (const float*)d_in[0];
    const float* K      = (const float*)d_in[1];
    const float* V      = (const float*)d_in[2];
    const float* wq     = (const float*)d_in[4];
    const float* wk     = (const float*)d_in[5];
    const float* wbq    = (const float*)d_in[6];
    const float* wbk    = (const float*)d_in[7];
    const float* cq3_w  = (const float*)d_in[8];
    const float* cq3_b  = (const float*)d_in[9];
    const float* cq9_w  = (const float*)d_in[10];
    const float* cq9_b  = (const float*)d_in[11];
    const float* ck3_w  = (const float*)d_in[12];
    const float* ck3_b  = (const float*)d_in[13];
    const float* ck9_w  = (const float*)d_in[14];
    const float* ck9_b  = (const float*)d_in[15];
    const float* bnq3_g = (const float*)d_in[16];
    const float* bnq3_b = (const float*)d_in[17];
    const float* bnq9_g = (const float*)d_in[18];
    const float* bnq9_b = (const float*)d_in[19];
    const float* bnk3_g = (const float*)d_in[20];
    const float* bnk3_b = (const float*)d_in[21];
    const float* bnk9_g = (const float*)d_in[22];
    const float* bnk9_b = (const float*)d_in[23];
    float* out = (float*)d_out;
    float* ws  = (float*)d_ws;

    hipMemsetAsync(ws + ST_OFF, 0, 64 * sizeof(float), stream);

    k_proj<<<32769, 256, 0, stream>>>(Q, K, wq, wk, wbq, wbk, ws);
    k_vpack<<<2048, 256, 0, stream>>>(V, ws);
    k_conv<<<256, 256, 0, stream>>>(ws, cq3_w, cq3_b, cq9_w, cq9_b,
                                    ck3_w, ck3_b, ck9_w, ck9_b);
    k_bnsm<<<256, 256, 0, stream>>>(ws, bnq3_g, bnq3_b, bnq9_g, bnq9_b,
                                    bnk3_g, bnk3_b, bnk9_g, bnk9_b);
    k_mix<<<512, 256, 0, stream>>>(ws);
    k_attn<<<1024, 256, 0, stream>>>(out, ws);
}